// Round 3
// baseline (59.413 us; speedup 1.0000x reference)
//
#include <hip/hip_runtime.h>
#include <math.h>

#define H 64
#define W 64
#define C 256
#define NB 2
#define SS 32
#define HW (H*W)

// ---------------- Kernel 1: [N,C,H,W] -> [N,H,W,C] transpose (both feats) ----
__global__ __launch_bounds__(256) void transpose_kernel(
    const float* __restrict__ feat1, const float* __restrict__ feat2,
    float* __restrict__ f1t, float* __restrict__ f2t) {
  __shared__ float tile[32][33];
  int z = blockIdx.z;                       // 0,1: feat1 n=0,1 ; 2,3: feat2 n=0,1
  const float* src = (z < NB ? feat1 : feat2) + (size_t)(z & 1) * (C * HW);
  float*       dst = (z < NB ? f1t   : f2t  ) + (size_t)(z & 1) * (C * HW);
  int p0 = blockIdx.x * 32;                 // spatial base (h*W+w)
  int c0 = blockIdx.y * 32;                 // channel base
  int tx = threadIdx.x, ty = threadIdx.y;   // block (32,8)
#pragma unroll
  for (int j = 0; j < 4; ++j) {
    int cc = c0 + ty + j * 8;
    tile[ty + j * 8][tx] = src[(size_t)cc * HW + p0 + tx];
  }
  __syncthreads();
#pragma unroll
  for (int j = 0; j < 4; ++j) {
    int pp = p0 + ty + j * 8;
    dst[(size_t)pp * C + c0 + tx] = tile[tx][ty + j * 8];
  }
}

// ---------------- Kernel 2: fundamental matrix per batch (fp64) --------------
__global__ void fmat_kernel(const float* __restrict__ P1f,
                            const float* __restrict__ P2f,
                            double* __restrict__ Fout) {
  int n = threadIdx.x;
  if (n >= NB) return;
  double p1[3][4], p2[3][4];
  for (int i = 0; i < 3; ++i)
    for (int j = 0; j < 4; ++j) {
      p1[i][j] = (double)P1f[n * 12 + i * 4 + j];
      p2[i][j] = (double)P2f[n * 12 + i * 4 + j];
    }
  double A[3][3];
  for (int i = 0; i < 3; ++i)
    for (int j = 0; j < 3; ++j) {
      double s = 0;
      for (int k = 0; k < 4; ++k) s += p1[i][k] * p1[j][k];
      A[i][j] = s;
    }
  double det = A[0][0] * (A[1][1] * A[2][2] - A[1][2] * A[2][1])
             - A[0][1] * (A[1][0] * A[2][2] - A[1][2] * A[2][0])
             + A[0][2] * (A[1][0] * A[2][1] - A[1][1] * A[2][0]);
  double id = 1.0 / det;
  double Ai[3][3];
  Ai[0][0] = (A[1][1] * A[2][2] - A[1][2] * A[2][1]) * id;
  Ai[0][1] = (A[0][2] * A[2][1] - A[0][1] * A[2][2]) * id;
  Ai[0][2] = (A[0][1] * A[1][2] - A[0][2] * A[1][1]) * id;
  Ai[1][0] = (A[1][2] * A[2][0] - A[1][0] * A[2][2]) * id;
  Ai[1][1] = (A[0][0] * A[2][2] - A[0][2] * A[2][0]) * id;
  Ai[1][2] = (A[0][2] * A[1][0] - A[0][0] * A[1][2]) * id;
  Ai[2][0] = (A[1][0] * A[2][1] - A[1][1] * A[2][0]) * id;
  Ai[2][1] = (A[0][1] * A[2][0] - A[0][0] * A[2][1]) * id;
  Ai[2][2] = (A[0][0] * A[1][1] - A[0][1] * A[1][0]) * id;
  double Pi[4][3];
  for (int i = 0; i < 4; ++i)
    for (int j = 0; j < 3; ++j) {
      double s = 0;
      for (int k = 0; k < 3; ++k) s += p1[k][i] * Ai[k][j];
      Pi[i][j] = s;
    }
  double M[3][3];
  for (int i = 0; i < 3; ++i)
    for (int j = 0; j < 3; ++j) {
      double s = 0;
      for (int k = 0; k < 4; ++k) s += p2[i][k] * Pi[k][j];
      M[i][j] = s;
    }
  double nv[4];
  {
    auto det3 = [&](int ca, int cb, int cc) {
      return p1[0][ca] * (p1[1][cb] * p1[2][cc] - p1[1][cc] * p1[2][cb])
           - p1[0][cb] * (p1[1][ca] * p1[2][cc] - p1[1][cc] * p1[2][ca])
           + p1[0][cc] * (p1[1][ca] * p1[2][cb] - p1[1][cb] * p1[2][ca]);
    };
    nv[0] =  det3(1, 2, 3);
    nv[1] = -det3(0, 2, 3);
    nv[2] =  det3(0, 1, 3);
    nv[3] = -det3(0, 1, 2);
  }
  double nn = sqrt(nv[0]*nv[0] + nv[1]*nv[1] + nv[2]*nv[2] + nv[3]*nv[3]);
  for (int i = 0; i < 4; ++i) nv[i] /= nn;
  double e2[3];
  for (int i = 0; i < 3; ++i) {
    double s = 0;
    for (int j = 0; j < 4; ++j) s += p2[i][j] * nv[j];
    e2[i] = s;
  }
  for (int j = 0; j < 3; ++j) {
    Fout[n * 9 + 0 * 3 + j] = -e2[2] * M[1][j] + e2[1] * M[2][j];
    Fout[n * 9 + 1 * 3 + j] =  e2[2] * M[0][j] - e2[0] * M[2][j];
    Fout[n * 9 + 2 * 3 + j] = -e2[1] * M[0][j] + e2[0] * M[1][j];
  }
}

// ------- Kernel 3: 4 px/wave, 16 lanes/px, 16 ch/lane, 2 waves split S ------
// XCD pinning: blockIdx%8 selects XCD; XCD 0-3 -> image 0, XCD 4-7 -> image 1.
__global__ __launch_bounds__(256) void epi_main(
    const float* __restrict__ f1t, const float* __restrict__ f2t,
    const double* __restrict__ Fd, float* __restrict__ out) {
  const int tid  = threadIdx.x;
  const int lane = tid & 63;
  const int wv   = tid >> 6;
  const int grp  = lane >> 4;               // pixel within cluster (0..3)
  const int cl   = lane & 15;               // channel-group lane (0..15)
  const int half = wv & 1;                  // which S-half this wave computes
  const int clA  = wv >> 1;                 // cluster within block (0..1)
  const int bid  = blockIdx.x;
  const int n    = (bid >> 2) & 1;          // image pinned to XCD group
  const int c8   = (bid >> 3) * 4 + (bid & 3);   // [0,512) cluster-of-8 index
  const int p    = c8 * 8 + clA * 4 + grp;  // pixel within image [0,4096)
  const int h = p >> 6, w = p & (W - 1);

  // --- epipolar line + endpoint pick, fp32 ---
  const double* Fdp = Fd + n * 9;
  const float F0 = (float)Fdp[0], F1 = (float)Fdp[1], F2 = (float)Fdp[2];
  const float F3 = (float)Fdp[3], F4 = (float)Fdp[4], F5 = (float)Fdp[5];
  const float F6 = (float)Fdp[6], F7 = (float)Fdp[7], F8 = (float)Fdp[8];
  const float X = w * 4.0f + 1.5f;
  const float Y = h * 4.0f + 1.5f;
  const float a = F0 * X + F1 * Y + F2;
  const float b = F3 * X + F4 * Y + F5;
  const float c = F6 * X + F7 * Y + F8;
  const float a_s = (fabsf(a) < 1e-3f) ? 1e-3f : a;
  const float b_s = (fabsf(b) < 1e-3f) ? 1e-3f : b;
  const float xmin = 1.5f, xmax = 253.5f, ymin = 1.5f, ymax = 253.5f, tol = 0.01f;
  float cx[4], cy[4];
  cx[0] = xmin;  cy[0] = -(c + a * xmin) / b_s;
  cx[1] = xmax;  cy[1] = -(c + a * xmax) / b_s;
  cx[2] = -(c + b * ymin) / a_s;  cy[2] = ymin;
  cx[3] = -(c + b * ymax) / a_s;  cy[3] = ymax;
  bool valid[4];
#pragma unroll
  for (int i = 0; i < 4; ++i)
    valid[i] = (cx[i] >= xmin - tol) && (cx[i] <= xmax + tol) &&
               (cy[i] >= ymin - tol) && (cy[i] <= ymax + tol);
#pragma unroll
  for (int i = 0; i < 4; ++i)
    if (!valid[i]) { cx[i] = xmin - 10000.0f; cy[i] = ymin - 10000.0f; }
  int pk0 = -1, pk1 = -1;
#pragma unroll
  for (int i = 0; i < 4; ++i)
    if (valid[i]) { if (pk0 < 0) pk0 = i; else if (pk1 < 0) pk1 = i; }
#pragma unroll
  for (int i = 0; i < 4; ++i)
    if (!valid[i]) { if (pk0 < 0) pk0 = i; else if (pk1 < 0) pk1 = i; }
  // endpoints in destination-pixel coords: x=(px-1.5)*0.25
  const float x0p = (cx[pk0] - 1.5f) * 0.25f;
  const float y0p = (cy[pk0] - 1.5f) * 0.25f;
  const float pdx = (cx[pk1] - 1.5f) * 0.25f - x0p;
  const float pdy = (cy[pk1] - 1.5f) * 0.25f - y0p;

  // --- per-lane: 16 channels as 4x float4 ---
  const float* f1b = f1t + ((size_t)n * HW + p) * C + cl * 4;
  const float4 f1v0 = *(const float4*)(f1b +   0);
  const float4 f1v1 = *(const float4*)(f1b +  64);
  const float4 f1v2 = *(const float4*)(f1b + 128);
  const float4 f1v3 = *(const float4*)(f1b + 192);
  const float* f2b = f2t + (size_t)n * HW * C + cl * 4;

  float m = -INFINITY, l = 0.f;
  float4 acc0 = {0,0,0,0}, acc1 = {0,0,0,0}, acc2 = {0,0,0,0}, acc3 = {0,0,0,0};
  const float sbase = (float)(half * (SS / 2));

#pragma unroll 2
  for (int j = 0; j < SS / 2; ++j) {
    const float t = (sbase + (float)j) * (1.0f / 31.0f);
    const float x = fmaf(t, pdx, x0p);
    const float y = fmaf(t, pdy, y0p);
    const float xf = floorf(x), yf = floorf(y);
    const float wx = x - xf, wy = y - yf;
    const int x0 = (int)xf, y0 = (int)yf;
    const int x1 = x0 + 1, y1 = y0 + 1;
    const bool bx0 = ((unsigned)x0 < W), bx1 = ((unsigned)x1 < W);
    const bool by0 = ((unsigned)y0 < H), by1 = ((unsigned)y1 < H);
    const int xc0 = min(max(x0, 0), W - 1), xc1 = min(max(x1, 0), W - 1);
    const int yc0 = min(max(y0, 0), H - 1), yc1 = min(max(y1, 0), H - 1);
    const float u0 = 1.f - wx, v0 = 1.f - wy;
    const float w00 = v0 * u0 * (float)(bx0 & by0);
    const float w01 = v0 * wx * (float)(bx1 & by0);
    const float w10 = wy * u0 * (float)(bx0 & by1);
    const float w11 = wy * wx * (float)(bx1 & by1);
    const float* p00 = f2b + (size_t)((yc0 * W + xc0) * C);
    const float* p01 = f2b + (size_t)((yc0 * W + xc1) * C);
    const float* p10 = f2b + (size_t)((yc1 * W + xc0) * C);
    const float* p11 = f2b + (size_t)((yc1 * W + xc1) * C);

    float part = 0.f;
    float4 q0, q1, q2, q3;
#define CHUNK(OFF, F1V, Q)                                               \
    {                                                                    \
      const float4 s00 = *(const float4*)(p00 + OFF);                    \
      const float4 s01 = *(const float4*)(p01 + OFF);                    \
      const float4 s10 = *(const float4*)(p10 + OFF);                    \
      const float4 s11 = *(const float4*)(p11 + OFF);                    \
      Q.x = w00*s00.x + w01*s01.x + w10*s10.x + w11*s11.x;               \
      Q.y = w00*s00.y + w01*s01.y + w10*s10.y + w11*s11.y;               \
      Q.z = w00*s00.z + w01*s01.z + w10*s10.z + w11*s11.z;               \
      Q.w = w00*s00.w + w01*s01.w + w10*s10.w + w11*s11.w;               \
      part += F1V.x*Q.x + F1V.y*Q.y + F1V.z*Q.z + F1V.w*Q.w;             \
    }
    CHUNK(  0, f1v0, q0)
    CHUNK( 64, f1v1, q1)
    CHUNK(128, f1v2, q2)
    CHUNK(192, f1v3, q3)
#undef CHUNK
    part += __shfl_xor(part, 1);
    part += __shfl_xor(part, 2);
    part += __shfl_xor(part, 4);
    part += __shfl_xor(part, 8);

    // branchless online-softmax update
    const float mn = fmaxf(m, part);
    const float sc = __expf(m - mn);       // ==1 when max unchanged; 0 at first iter
    const float e  = __expf(part - mn);
    l = fmaf(l, sc, e);
    acc0.x = fmaf(acc0.x, sc, e * q0.x); acc0.y = fmaf(acc0.y, sc, e * q0.y);
    acc0.z = fmaf(acc0.z, sc, e * q0.z); acc0.w = fmaf(acc0.w, sc, e * q0.w);
    acc1.x = fmaf(acc1.x, sc, e * q1.x); acc1.y = fmaf(acc1.y, sc, e * q1.y);
    acc1.z = fmaf(acc1.z, sc, e * q1.z); acc1.w = fmaf(acc1.w, sc, e * q1.w);
    acc2.x = fmaf(acc2.x, sc, e * q2.x); acc2.y = fmaf(acc2.y, sc, e * q2.y);
    acc2.z = fmaf(acc2.z, sc, e * q2.z); acc2.w = fmaf(acc2.w, sc, e * q2.w);
    acc3.x = fmaf(acc3.x, sc, e * q3.x); acc3.y = fmaf(acc3.y, sc, e * q3.y);
    acc3.z = fmaf(acc3.z, sc, e * q3.z); acc3.w = fmaf(acc3.w, sc, e * q3.w);
    m = mn;
  }

  // --- merge the two S-halves via LDS (exact online-softmax merge) ---
  __shared__ float4 lsm[2][64][5];
  if (half) {
    lsm[clA][lane][0] = acc0;
    lsm[clA][lane][1] = acc1;
    lsm[clA][lane][2] = acc2;
    lsm[clA][lane][3] = acc3;
    lsm[clA][lane][4] = make_float4(m, l, 0.f, 0.f);
  }
  __syncthreads();
  if (!half) {
    const float4 b0 = lsm[clA][lane][0];
    const float4 b1 = lsm[clA][lane][1];
    const float4 b2 = lsm[clA][lane][2];
    const float4 b3 = lsm[clA][lane][3];
    const float4 ml = lsm[clA][lane][4];
    const float mo = ml.x, lo = ml.y;
    const float mf = fmaxf(m, mo);
    const float s0 = __expf(m - mf), s1 = __expf(mo - mf);
    const float L = l * s0 + lo * s1;
    const float inv = 1.0f / L;
    float* ob = out + (size_t)n * C * HW + p + (size_t)(cl * 4) * HW;
#define STORE(J, ACC, BCC)                                           \
    ob[(size_t)(64*J + 0) * HW] = (ACC.x * s0 + BCC.x * s1) * inv;   \
    ob[(size_t)(64*J + 1) * HW] = (ACC.y * s0 + BCC.y * s1) * inv;   \
    ob[(size_t)(64*J + 2) * HW] = (ACC.z * s0 + BCC.z * s1) * inv;   \
    ob[(size_t)(64*J + 3) * HW] = (ACC.w * s0 + BCC.w * s1) * inv;
    STORE(0, acc0, b0) STORE(1, acc1, b1) STORE(2, acc2, b2) STORE(3, acc3, b3)
#undef STORE
  }
}

extern "C" void kernel_launch(void* const* d_in, const int* in_sizes, int n_in,
                              void* d_out, int out_size, void* d_ws, size_t ws_size,
                              hipStream_t stream) {
  const float* feat1 = (const float*)d_in[0];
  const float* feat2 = (const float*)d_in[1];
  const float* P1 = (const float*)d_in[2];
  const float* P2 = (const float*)d_in[3];
  float* out = (float*)d_out;

  char* ws = (char*)d_ws;
  const size_t feat_bytes = (size_t)NB * HW * C * sizeof(float);  // 8 MB
  float*  f2t = (float*)ws;
  float*  f1t = (float*)(ws + feat_bytes);
  double* Fd  = (double*)(ws + 2 * feat_bytes);

  fmat_kernel<<<1, 64, 0, stream>>>(P1, P2, Fd);
  transpose_kernel<<<dim3(HW / 32, C / 32, 2 * NB), dim3(32, 8), 0, stream>>>(
      feat1, feat2, f1t, f2t);
  epi_main<<<NB * HW / 8, 256, 0, stream>>>(f1t, f2t, Fd, out);
}